// Round 1
// baseline (824.121 us; speedup 1.0000x reference)
//
#include <hip/hip_runtime.h>
#include <math.h>

// Problem constants (from reference): N=100000, H=256, E=3200000, OUT=2
#define HDIM 256
#define NEG_SLOPE 0.2f

// ---------------- Kernel 1: per-node z, el, er + init accumulators -------------
// One 64-lane wave per node; lane i handles input elements 4i..4i+3 (float4).
// W is [H,2] row-major: element k, col j at flat 2k+j. Lane i needs floats
// 8i..8i+7 => two float4s at indices 2i, 2i+1.
__global__ void k_node(const float* __restrict__ input,
                       const float* __restrict__ W,
                       const float* __restrict__ attn_l,
                       const float* __restrict__ attn_r,
                       float* __restrict__ z,        // [2n] interleaved
                       float* __restrict__ el,
                       float* __restrict__ er,
                       unsigned* __restrict__ m_enc,
                       float* __restrict__ denom,
                       float* __restrict__ outacc,   // [2n]
                       int n)
{
    int node = blockIdx.x * 4 + (threadIdx.x >> 6);
    int lane = threadIdx.x & 63;
    if (node >= n) return;

    const float4* inrow = (const float4*)(input + (size_t)node * HDIM);
    float4 v = inrow[lane];
    const float4* Wv = (const float4*)W;
    float4 w0 = Wv[2 * lane];
    float4 w1 = Wv[2 * lane + 1];
    // k=4*lane+0: (w0.x,w0.y) ; +1: (w0.z,w0.w) ; +2: (w1.x,w1.y) ; +3: (w1.z,w1.w)
    float s0 = v.x * w0.x + v.y * w0.z + v.z * w1.x + v.w * w1.z;
    float s1 = v.x * w0.y + v.y * w0.w + v.z * w1.y + v.w * w1.w;

    #pragma unroll
    for (int off = 32; off > 0; off >>= 1) {
        s0 += __shfl_xor(s0, off);
        s1 += __shfl_xor(s1, off);
    }

    if (lane == 0) {
        z[2 * node]     = s0;
        z[2 * node + 1] = s1;
        el[node] = s0 * attn_l[0] + s1 * attn_l[1];
        er[node] = s0 * attn_r[0] + s1 * attn_r[1];
        m_enc[node] = 0x007FFFFFu;   // order-preserving encoding of -inf
        denom[node] = 0.0f;
        outacc[2 * node]     = 0.0f;
        outacc[2 * node + 1] = 0.0f;
    }
}

__device__ __forceinline__ float leaky(float v) {
    return v >= 0.0f ? v : NEG_SLOPE * v;
}

// order-preserving float<->uint encoding for atomicMax over signed floats
__device__ __forceinline__ unsigned enc_f32(float f) {
    unsigned b = __float_as_uint(f);
    return b ^ ((b >> 31) ? 0xFFFFFFFFu : 0x80000000u);
}
__device__ __forceinline__ float dec_f32(unsigned u) {
    u ^= ((u >> 31) ? 0x80000000u : 0xFFFFFFFFu);
    return __uint_as_float(u);
}

// ---------------- Kernel 2: per-edge segment max -------------------------------
__global__ void k_edge_max(const int* __restrict__ src,
                           const int* __restrict__ dst,
                           const float* __restrict__ el,
                           const float* __restrict__ er,
                           unsigned* __restrict__ m_enc,
                           int e)
{
    int i = blockIdx.x * blockDim.x + threadIdx.x;
    if (i >= e) return;
    int s = src[i], d = dst[i];
    float v = leaky(el[s] + er[d]);
    atomicMax(m_enc + d, enc_f32(v));
}

// ---------------- Kernel 3: per-edge exp + denom + unnormalized accumulate -----
__global__ void k_edge_acc(const int* __restrict__ src,
                           const int* __restrict__ dst,
                           const float* __restrict__ el,
                           const float* __restrict__ er,
                           const unsigned* __restrict__ m_enc,
                           const float* __restrict__ z,   // [2n]
                           float* __restrict__ denom,
                           float* __restrict__ outacc,    // [2n]
                           int e)
{
    int i = blockIdx.x * blockDim.x + threadIdx.x;
    if (i >= e) return;
    int s = src[i], d = dst[i];
    float v = leaky(el[s] + er[d]);
    float m = dec_f32(m_enc[d]);
    float ex = __expf(v - m);
    atomicAdd(denom + d, ex);
    atomicAdd(outacc + 2 * d,     ex * z[2 * s]);
    atomicAdd(outacc + 2 * d + 1, ex * z[2 * s + 1]);
}

// ---------------- Kernel 4: epilogue gate --------------------------------------
// coff = outacc/denom + bias; std=relu(c0); mean=relu(c1);
// out = input * sigmoid(x*std + mean)
__global__ void k_final(const float* __restrict__ input,
                        const float* __restrict__ x,
                        const float* __restrict__ denom,
                        const float* __restrict__ outacc,
                        const float* __restrict__ bias,
                        float* __restrict__ out,
                        int n)
{
    int node = blockIdx.x * 4 + (threadIdx.x >> 6);
    int lane = threadIdx.x & 63;
    if (node >= n) return;

    float dn = denom[node];
    float b0 = bias[0], b1 = bias[1];
    float c0, c1;
    if (dn > 0.0f) {
        float inv = 1.0f / dn;
        c0 = outacc[2 * node] * inv + b0;
        c1 = outacc[2 * node + 1] * inv + b1;
    } else {          // no in-edges: segment sums are 0 -> coff = bias
        c0 = b0;
        c1 = b1;
    }
    float stdv  = fmaxf(c0, 0.0f);
    float meanv = fmaxf(c1, 0.0f);
    float t = x[node] * stdv + meanv;
    float g = 1.0f / (1.0f + __expf(-t));

    const float4* inrow = (const float4*)(input + (size_t)node * HDIM);
    float4* outrow = (float4*)(out + (size_t)node * HDIM);
    float4 v = inrow[lane];
    outrow[lane] = make_float4(v.x * g, v.y * g, v.z * g, v.w * g);
}

extern "C" void kernel_launch(void* const* d_in, const int* in_sizes, int n_in,
                              void* d_out, int out_size, void* d_ws, size_t ws_size,
                              hipStream_t stream)
{
    const float* input  = (const float*)d_in[0];  // [N,256]
    const float* x      = (const float*)d_in[1];  // [N,1]
    // d_in[2] = degree (unused)
    const int* esrc     = (const int*)d_in[3];    // [E]
    const int* edst     = (const int*)d_in[4];    // [E]
    const float* W      = (const float*)d_in[5];  // [256,2]
    const float* attn_l = (const float*)d_in[6];  // [2]
    const float* attn_r = (const float*)d_in[7];  // [2]
    const float* bias   = (const float*)d_in[8];  // [2]
    float* out = (float*)d_out;

    const int n = in_sizes[1];      // 100000
    const int e = in_sizes[3];      // 3200000

    // Workspace layout (floats): z[2n] | el[n] | er[n] | m_enc[n] | denom[n] | outacc[2n]
    float* ws = (float*)d_ws;
    float*    z      = ws;
    float*    el     = ws + 2 * (size_t)n;
    float*    er     = ws + 3 * (size_t)n;
    unsigned* m_enc  = (unsigned*)(ws + 4 * (size_t)n);
    float*    denom  = ws + 5 * (size_t)n;
    float*    outacc = ws + 6 * (size_t)n;

    dim3 blk(256);
    int nodeBlocks = (n + 3) / 4;
    int edgeBlocks = (e + 255) / 256;

    k_node<<<nodeBlocks, blk, 0, stream>>>(input, W, attn_l, attn_r,
                                           z, el, er, m_enc, denom, outacc, n);
    k_edge_max<<<edgeBlocks, blk, 0, stream>>>(esrc, edst, el, er, m_enc, e);
    k_edge_acc<<<edgeBlocks, blk, 0, stream>>>(esrc, edst, el, er, m_enc, z,
                                               denom, outacc, e);
    k_final<<<nodeBlocks, blk, 0, stream>>>(input, x, denom, outacc, bias, out, n);
}

// Round 3
// 693.306 us; speedup vs baseline: 1.1887x; 1.1887x over previous
//
#include <hip/hip_runtime.h>
#include <math.h>

// Problem constants (from reference): N=100000, H=256, E=3200000, OUT=2
#define HDIM 256
#define NEG_SLOPE 0.2f

// Workspace layout:
//   acc8     : 8 * n * float4   (acc0, acc1, denom, pad)  -- one copy per XCD
//   nodeinfo : n * float4       (el, er, z0, z1)
//   er       : n * float        (er only, for cheap dst gather)
//   g        : n * float        (final per-node gate)
// Total = 152n bytes = 15.2 MB.

__device__ __forceinline__ float leaky(float v) {
    return v >= 0.0f ? v : NEG_SLOPE * v;
}

// Raw fp32 atomic add, NO sc1 bit -> executes in the local (XCD) L2 without
// forwarding to the device coherence point. Only valid because each XCD gets
// its own accumulator copy (selected by HW_REG_XCC_ID below).
__device__ __forceinline__ void atomic_add_l2(float* addr, float val) {
    asm volatile("global_atomic_add_f32 %0, %1, off"
                 :: "v"(addr), "v"(val) : "memory");
}

// ---------------- Kernel 1: per-node z, el, er --------------------------------
// One 64-lane wave per node; lane i handles input elements 4i..4i+3 (float4).
// W is [H,2] row-major: element k, col j at flat 2k+j.
__global__ void k_node(const float* __restrict__ input,
                       const float* __restrict__ W,
                       const float* __restrict__ attn_l,
                       const float* __restrict__ attn_r,
                       float4* __restrict__ nodeinfo,  // (el, er, z0, z1)
                       float* __restrict__ er_arr,
                       int n)
{
    int node = blockIdx.x * 4 + (threadIdx.x >> 6);
    int lane = threadIdx.x & 63;
    if (node >= n) return;

    const float4* inrow = (const float4*)(input + (size_t)node * HDIM);
    float4 v = inrow[lane];
    const float4* Wv = (const float4*)W;
    float4 w0 = Wv[2 * lane];
    float4 w1 = Wv[2 * lane + 1];
    float s0 = v.x * w0.x + v.y * w0.z + v.z * w1.x + v.w * w1.z;
    float s1 = v.x * w0.y + v.y * w0.w + v.z * w1.y + v.w * w1.w;

    #pragma unroll
    for (int off = 32; off > 0; off >>= 1) {
        s0 += __shfl_xor(s0, off);
        s1 += __shfl_xor(s1, off);
    }

    if (lane == 0) {
        float el = s0 * attn_l[0] + s1 * attn_l[1];
        float er = s0 * attn_r[0] + s1 * attn_r[1];
        nodeinfo[node] = make_float4(el, er, s0, s1);
        er_arr[node] = er;
    }
}

// ---------------- Kernel 2: fused edge pass, XCD-local atomics -----------------
// No max-subtraction: scores bounded (|e| <~ 12), exp stays in fp32 range,
// alphas mathematically identical. Each workgroup accumulates into the copy
// belonging to the XCD it physically runs on; those atomics stay in local L2.
__global__ void k_edge(const int* __restrict__ src,
                       const int* __restrict__ dst,
                       const float4* __restrict__ nodeinfo,
                       const float* __restrict__ er_arr,
                       float4* __restrict__ acc8,   // 8 copies of [n] float4
                       int n, int e)
{
    unsigned xcc;
    asm("s_getreg_b32 %0, hwreg(HW_REG_XCC_ID)" : "=s"(xcc));
    float4* acc = acc8 + (size_t)(xcc & 7) * n;

    int i = blockIdx.x * blockDim.x + threadIdx.x;
    if (i >= e) return;
    int s = src[i], d = dst[i];
    float4 ns = nodeinfo[s];          // el, er, z0, z1
    float ex = __expf(leaky(ns.x + er_arr[d]));
    float* a = (float*)(acc + d);
    atomic_add_l2(a,     ex * ns.z);
    atomic_add_l2(a + 1, ex * ns.w);
    atomic_add_l2(a + 2, ex);
}

// ---------------- Kernel 3: reduce 8 copies + gate scalar ----------------------
__global__ void k_reduce(const float4* __restrict__ acc8,
                         const float* __restrict__ x,
                         const float* __restrict__ bias,
                         float* __restrict__ g,
                         int n)
{
    int i = blockIdx.x * blockDim.x + threadIdx.x;
    if (i >= n) return;
    float a0 = 0.0f, a1 = 0.0f, dn = 0.0f;
    #pragma unroll
    for (int xj = 0; xj < 8; ++xj) {
        float4 a = acc8[(size_t)xj * n + i];
        a0 += a.x; a1 += a.y; dn += a.z;
    }
    float c0 = bias[0], c1 = bias[1];
    if (dn > 0.0f) {
        float inv = 1.0f / dn;
        c0 = a0 * inv + c0;
        c1 = a1 * inv + c1;
    }
    float t = x[i] * fmaxf(c0, 0.0f) + fmaxf(c1, 0.0f);
    g[i] = 1.0f / (1.0f + __expf(-t));
}

// ---------------- Kernel 4: out = input * g[node] ------------------------------
__global__ void k_final(const float* __restrict__ input,
                        const float* __restrict__ g,
                        float* __restrict__ out,
                        int n)
{
    int node = blockIdx.x * 4 + (threadIdx.x >> 6);
    int lane = threadIdx.x & 63;
    if (node >= n) return;
    float gg = g[node];
    const float4* inrow = (const float4*)(input + (size_t)node * HDIM);
    float4* outrow = (float4*)(out + (size_t)node * HDIM);
    float4 v = inrow[lane];
    outrow[lane] = make_float4(v.x * gg, v.y * gg, v.z * gg, v.w * gg);
}

extern "C" void kernel_launch(void* const* d_in, const int* in_sizes, int n_in,
                              void* d_out, int out_size, void* d_ws, size_t ws_size,
                              hipStream_t stream)
{
    const float* input  = (const float*)d_in[0];  // [N,256]
    const float* x      = (const float*)d_in[1];  // [N,1]
    // d_in[2] = degree (unused)
    const int* esrc     = (const int*)d_in[3];    // [E]
    const int* edst     = (const int*)d_in[4];    // [E]
    const float* W      = (const float*)d_in[5];  // [256,2]
    const float* attn_l = (const float*)d_in[6];  // [2]
    const float* attn_r = (const float*)d_in[7];  // [2]
    const float* bias   = (const float*)d_in[8];  // [2]
    float* out = (float*)d_out;

    const int n = in_sizes[1];      // 100000
    const int e = in_sizes[3];      // 3200000

    char* ws = (char*)d_ws;
    float4* acc8     = (float4*)ws;                         // 8n float4
    float4* nodeinfo = (float4*)(ws + (size_t)n * 128);     // n float4
    float*  er_arr   = (float*)(ws + (size_t)n * 144);      // n float
    float*  g        = (float*)(ws + (size_t)n * 148);      // n float

    // zero the 8 accumulator copies (re-poisoned to 0xAA before every launch)
    hipMemsetAsync(acc8, 0, (size_t)n * 128, stream);

    dim3 blk(256);
    int nodeBlocks = (n + 3) / 4;
    int edgeBlocks = (e + 255) / 256;
    int flatBlocks = (n + 255) / 256;

    k_node<<<nodeBlocks, blk, 0, stream>>>(input, W, attn_l, attn_r,
                                           nodeinfo, er_arr, n);
    k_edge<<<edgeBlocks, blk, 0, stream>>>(esrc, edst, nodeinfo, er_arr,
                                           acc8, n, e);
    k_reduce<<<flatBlocks, blk, 0, stream>>>(acc8, x, bias, g, n);
    k_final<<<nodeBlocks, blk, 0, stream>>>(input, g, out, n);
}

// Round 4
// 541.062 us; speedup vs baseline: 1.5232x; 1.2814x over previous
//
#include <hip/hip_runtime.h>
#include <hip/hip_fp16.h>
#include <math.h>

// Problem constants (from reference): N=100000, H=256, E=3200000, OUT=2
#define HDIM 256
#define NEG_SLOPE 0.2f

// Bottleneck model (R1/R3 evidence): global fp atomics are memory-side RMWs,
// walled at ~20.3 G requests/s (WRITE_SIZE == 32B * request count, duration
// invariant to locality/copies). So: minimize atomic REQUESTS per edge.
// This version: 2 requests/edge = 1x global_atomic_pk_add_f16 (both
// numerators) + 1x global_atomic_add_f32 (denom).
//
// f16 safety: shift scores by the per-dst upper bound leaky(M_el + er_d),
// where M_el = max_s el_s (global scalar). exp' in (0,1], sums bounded by
// degree*|z| ~ 3e2 << 65504; dominant term per node >= ~5e-3 >> f16 denormal
// floor. Denominator stays fp32-exact; the shift cancels in the ratio.

__device__ __forceinline__ float leaky(float v) {
    return v >= 0.0f ? v : NEG_SLOPE * v;
}

// order-preserving float<->uint encoding for atomicMax over signed floats
__device__ __forceinline__ unsigned enc_f32(float f) {
    unsigned b = __float_as_uint(f);
    return b ^ ((b >> 31) ? 0xFFFFFFFFu : 0x80000000u);
}
__device__ __forceinline__ float dec_f32(unsigned u) {
    u ^= ((u >> 31) ? 0x80000000u : 0xFFFFFFFFu);
    return __uint_as_float(u);
}

// ---------------- Kernel 1: per-node z, el, er --------------------------------
// One 64-lane wave per node; lane i handles input elements 4i..4i+3 (float4).
// W is [H,2] row-major: element k, col j at flat 2k+j.
__global__ void k_node(const float* __restrict__ input,
                       const float* __restrict__ W,
                       const float* __restrict__ attn_l,
                       const float* __restrict__ attn_r,
                       float4* __restrict__ nodeinfo,  // (el, er, z0, z1)
                       float* __restrict__ el_arr,
                       float* __restrict__ er_arr,
                       int n)
{
    int node = blockIdx.x * 4 + (threadIdx.x >> 6);
    int lane = threadIdx.x & 63;
    if (node >= n) return;

    const float4* inrow = (const float4*)(input + (size_t)node * HDIM);
    float4 v = inrow[lane];
    const float4* Wv = (const float4*)W;
    float4 w0 = Wv[2 * lane];
    float4 w1 = Wv[2 * lane + 1];
    float s0 = v.x * w0.x + v.y * w0.z + v.z * w1.x + v.w * w1.z;
    float s1 = v.x * w0.y + v.y * w0.w + v.z * w1.y + v.w * w1.w;

    #pragma unroll
    for (int off = 32; off > 0; off >>= 1) {
        s0 += __shfl_xor(s0, off);
        s1 += __shfl_xor(s1, off);
    }

    if (lane == 0) {
        float el = s0 * attn_l[0] + s1 * attn_l[1];
        float er = s0 * attn_r[0] + s1 * attn_r[1];
        nodeinfo[node] = make_float4(el, er, s0, s1);
        el_arr[node] = el;
        er_arr[node] = er;
    }
}

// ---------------- Kernel 2: global max of el ----------------------------------
__global__ void k_maxel(const float* __restrict__ el, unsigned* __restrict__ M_enc, int n)
{
    float m = -1e30f;
    for (int i = blockIdx.x * blockDim.x + threadIdx.x; i < n;
         i += gridDim.x * blockDim.x)
        m = fmaxf(m, el[i]);
    #pragma unroll
    for (int off = 32; off > 0; off >>= 1)
        m = fmaxf(m, __shfl_xor(m, off));
    __shared__ float s[4];
    int lane = threadIdx.x & 63, w = threadIdx.x >> 6;
    if (lane == 0) s[w] = m;
    __syncthreads();
    if (threadIdx.x == 0) {
        float mm = fmaxf(fmaxf(s[0], s[1]), fmaxf(s[2], s[3]));
        atomicMax(M_enc, enc_f32(mm));   // M_enc pre-zeroed; enc(0)=0 acts as -inf
    }
}

// ---------------- Kernel 3: fused edge pass, 2 atomic requests/edge ------------
__global__ void k_edge(const int* __restrict__ src,
                       const int* __restrict__ dst,
                       const float4* __restrict__ nodeinfo,
                       const float* __restrict__ er_arr,
                       const unsigned* __restrict__ M_enc,
                       unsigned* __restrict__ num,    // [n] packed half2 (S0,S1)
                       float* __restrict__ denom,     // [n]
                       int e)
{
    int i = blockIdx.x * blockDim.x + threadIdx.x;
    if (i >= e) return;
    float Mel = dec_f32(*M_enc);
    int s = src[i], d = dst[i];
    float4 ns = nodeinfo[s];          // el, er, z0, z1
    float erd = er_arr[d];
    // shifted softmax term, in (0, 1]
    float ex = __expf(leaky(ns.x + erd) - leaky(Mel + erd));
    __half2 h = __floats2half2_rn(ex * ns.z, ex * ns.w);
    unsigned hv = *(unsigned*)&h;
    unsigned* np = num + d;
    asm volatile("global_atomic_pk_add_f16 %0, %1, off"
                 :: "v"(np), "v"(hv) : "memory");
    float* dp = denom + d;
    asm volatile("global_atomic_add_f32 %0, %1, off"
                 :: "v"(dp), "v"(ex) : "memory");
}

// ---------------- Kernel 4: coff + gate scalar ---------------------------------
__global__ void k_reduce(const unsigned* __restrict__ num,
                         const float* __restrict__ denom,
                         const float* __restrict__ x,
                         const float* __restrict__ bias,
                         float* __restrict__ g,
                         int n)
{
    int i = blockIdx.x * blockDim.x + threadIdx.x;
    if (i >= n) return;
    float D = denom[i];
    float c0 = bias[0], c1 = bias[1];
    if (D > 0.0f) {
        __half2 h = *(const __half2*)(num + i);
        float2 f = __half22float2(h);
        float inv = 1.0f / D;
        c0 += f.x * inv;
        c1 += f.y * inv;
    }
    float t = x[i] * fmaxf(c0, 0.0f) + fmaxf(c1, 0.0f);
    g[i] = 1.0f / (1.0f + __expf(-t));
}

// ---------------- Kernel 5: out = input * g[node] ------------------------------
__global__ void k_final(const float* __restrict__ input,
                        const float* __restrict__ g,
                        float* __restrict__ out,
                        int n)
{
    int node = blockIdx.x * 4 + (threadIdx.x >> 6);
    int lane = threadIdx.x & 63;
    if (node >= n) return;
    float gg = g[node];
    const float4* inrow = (const float4*)(input + (size_t)node * HDIM);
    float4* outrow = (float4*)(out + (size_t)node * HDIM);
    float4 v = inrow[lane];
    outrow[lane] = make_float4(v.x * gg, v.y * gg, v.z * gg, v.w * gg);
}

extern "C" void kernel_launch(void* const* d_in, const int* in_sizes, int n_in,
                              void* d_out, int out_size, void* d_ws, size_t ws_size,
                              hipStream_t stream)
{
    const float* input  = (const float*)d_in[0];  // [N,256]
    const float* x      = (const float*)d_in[1];  // [N,1]
    // d_in[2] = degree (unused)
    const int* esrc     = (const int*)d_in[3];    // [E]
    const int* edst     = (const int*)d_in[4];    // [E]
    const float* W      = (const float*)d_in[5];  // [256,2]
    const float* attn_l = (const float*)d_in[6];  // [2]
    const float* attn_r = (const float*)d_in[7];  // [2]
    const float* bias   = (const float*)d_in[8];  // [2]
    float* out = (float*)d_out;

    const int n = in_sizes[1];      // 100000
    const int e = in_sizes[3];      // 3200000

    // ws layout (bytes): num[4n] | denom[4n] | M_enc[4] | pad | nodeinfo[16n]
    //                    | el[4n] | er[4n] | g[4n]
    char* ws = (char*)d_ws;
    unsigned* num      = (unsigned*)ws;                          // 4n
    float*    denom    = (float*)(ws + (size_t)4 * n);           // 4n
    unsigned* M_enc    = (unsigned*)(ws + (size_t)8 * n);        // 4
    float4*   nodeinfo = (float4*)(ws + (size_t)8 * n + 16);     // 16n (16B aligned)
    float*    el_arr   = (float*)(ws + (size_t)24 * n + 16);     // 4n
    float*    er_arr   = (float*)(ws + (size_t)28 * n + 16);     // 4n
    float*    g        = (float*)(ws + (size_t)32 * n + 16);     // 4n

    // zero num, denom, M_enc in one shot (ws re-poisoned before every launch)
    hipMemsetAsync(ws, 0, (size_t)8 * n + 4, stream);

    dim3 blk(256);
    int nodeBlocks = (n + 3) / 4;
    int edgeBlocks = (e + 255) / 256;
    int flatBlocks = (n + 255) / 256;

    k_node<<<nodeBlocks, blk, 0, stream>>>(input, W, attn_l, attn_r,
                                           nodeinfo, el_arr, er_arr, n);
    k_maxel<<<120, blk, 0, stream>>>(el_arr, M_enc, n);
    k_edge<<<edgeBlocks, blk, 0, stream>>>(esrc, edst, nodeinfo, er_arr, M_enc,
                                           num, denom, e);
    k_reduce<<<flatBlocks, blk, 0, stream>>>(num, denom, x, bias, g, n);
    k_final<<<nodeBlocks, blk, 0, stream>>>(input, g, out, n);
}